// Round 13
// baseline (615.428 us; speedup 1.0000x reference)
//
#include <hip/hip_runtime.h>
#include <math.h>

// ---- problem constants ----
#define NCH   8
#define IMN   256
#define OSN   320
#define NPTS  (64*4096)            // 262144 trajectory points
#define BETA_F   10.9551078f       // pi*sqrt((6/1.25*0.75)^2 - 0.8)
#define BETA2_F  120.014389f       // BETA^2
#define APOD_C   0.05890486225f    // pi*WIDTH/OSN = pi*6/320

typedef unsigned int u32;

// float -> bf16 bits, round-to-nearest-even
__device__ __forceinline__ u32 f2bf(float f) {
    u32 u = __float_as_uint(f);
    return (u + 0x7FFFu + ((u >> 16) & 1u)) >> 16;
}

// Kaiser-Bessel i0 (Abramowitz & Stegun 9.8.1 / 9.8.2), rel err ~5e-7
__device__ __forceinline__ float i0f(float t) {
    if (t < 3.75f) {
        float y = t * t * (1.0f / 14.0625f);
        return 1.0f + y * (3.5156229f + y * (3.0899424f + y * (1.2067492f +
                     y * (0.2659732f + y * (0.0360768f + y * 0.0045813f)))));
    }
    float z = 3.75f / t;
    float p = 0.39894228f + z * (0.01328592f + z * (0.00225319f + z * (-0.00157565f +
              z * (0.00916281f + z * (-0.02057706f + z * (0.02635537f +
              z * (-0.01647633f + z * 0.00392377f)))))));
    return expf(t) * rsqrtf(t) * p;
}

__device__ __forceinline__ float apodf(int i) {
    float x = APOD_C * (float)(i - IMN / 2);
    float arg = sqrtf(BETA2_F - x * x);
    float e = expf(arg);
    float sh = 0.5f * (e - 1.0f / e);
    return arg / sh;
}

// W[m][n] = exp(-2*pi*i*m*n/320)
__global__ void build_w(float2* __restrict__ W) {
    int idx = blockIdx.x * 256 + threadIdx.x;
    if (idx >= OSN * OSN) return;
    int m = idx / OSN, n = idx - m * OSN;
    int p = (int)(((long)m * n) % OSN);
    float th = (2.0f * (float)M_PI / (float)OSN) * (float)p;
    float sn, cs;
    sincosf(th, &sn, &cs);
    W[idx] = make_float2(cs, -sn);
}

// xp[c][n1][n2] = apod(n1-32)*apod(n2-32)/256 * (img_r + i*img_i)[c][n1-32][n2-32]
__global__ void build_xp(const float* __restrict__ r, const float* __restrict__ im,
                         float2* __restrict__ xp) {
    long idx = (long)blockIdx.x * 256 + threadIdx.x;   // 0 .. 819199
    int n2 = (int)(idx % OSN);
    long q = idx / OSN;
    int n1 = (int)(q % OSN);
    int c  = (int)(q / OSN);
    float2 v = make_float2(0.f, 0.f);
    if (n1 >= 32 && n1 < 288 && n2 >= 32 && n2 < 288) {
        int i1 = n1 - 32, i2 = n2 - 32;
        long off = ((long)c * IMN + i1) * IMN + i2;
        float a = apodf(i1) * apodf(i2) * (1.0f / 256.0f);
        v = make_float2(r[off] * a, im[off] * a);
    }
    xp[idx] = v;
}

// Row DFT with literal ifftshift on reads:
//   R1[c][n1][m2] = sum_n2 xp[c][(n1+160)%320][(n2+160)%320] * W[m2][n2]
__global__ void dft_rows(const float2* __restrict__ xp, const float2* __restrict__ W,
                         float2* __restrict__ R1) {
    long g = (long)blockIdx.x * 256 + threadIdx.x;     // 0 .. 819199
    int m2 = (int)(g % OSN);
    long q = g / OSN;
    int n1 = (int)(q % OSN);
    int c  = (int)(q / OSN);
    int sn1 = (n1 + 160) % OSN;
    const float2* xrow = xp + ((long)c * OSN + sn1) * OSN;
    const float2* wrow = W + (long)m2 * OSN;
    float sr = 0.f, si = 0.f;
    for (int n2 = 0; n2 < OSN; n2++) {
        int sn2 = n2 + 160; if (sn2 >= OSN) sn2 -= OSN;
        float2 x = xrow[sn2];
        float2 w = wrow[n2];
        sr += x.x * w.x - x.y * w.y;
        si += x.x * w.y + x.y * w.x;
    }
    R1[g] = make_float2(sr, si);
}

// Col DFT + literal fftshift folded into the write:
//   Y[c][m1][m2] = sum_n1 R1[c][n1][m2] * W[m1][n1]
//   G[(m1+160)%320][(m2+160)%320][c] = Y[c][m1][m2]
__global__ void dft_cols(const float2* __restrict__ R1, const float2* __restrict__ W,
                         float2* __restrict__ G) {
    long g = (long)blockIdx.x * 256 + threadIdx.x;     // 0 .. 819199
    int m2 = (int)(g % OSN);
    long q = g / OSN;
    int m1 = (int)(q % OSN);
    int c  = (int)(q / OSN);
    const float2* wrow = W + (long)m1 * OSN;
    const float2* tcol = R1 + (long)c * OSN * OSN + m2;
    float sr = 0.f, si = 0.f;
    for (int n1 = 0; n1 < OSN; n1++) {
        float2 a = wrow[n1];
        float2 b = tcol[(long)n1 * OSN];
        sr += a.x * b.x - a.y * b.y;
        si += a.x * b.y + a.y * b.x;
    }
    int k1 = (m1 + 160) % OSN;
    int k2 = (m2 + 160) % OSN;
    G[((long)k1 * OSN + k2) * NCH + c] = make_float2(sr, si);
}

// KB interpolation. R13 HYPOTHESIS: output stores (imag, real) per point —
// equivalently the ref is i*conj(my base): the ONLY Hamming-2 convention
// combo (sign+ri) that keeps sample positions intact, matching 12 rounds
// of "decorrelated-at-position" failures. One-line change vs R9: pack
// im in low u16, re in high u16.  Base conventions otherwise: e^{-i},
// comp0 -> k1 (H), img_r=d_in[0], c-major interleaved output.
__global__ void interp_kernel(const float* __restrict__ trj,
                              const float2* __restrict__ grid,
                              u32* __restrict__ out) {
    const int t = threadIdx.x;
    const int c = t & 7;
    const int pl = t >> 3;
    const int pt = blockIdx.x * 32 + pl;

    float cx = __fadd_rn(__fmul_rn(trj[pt * 2 + 0], 1.25f), 160.0f);
    float cy = __fadd_rn(__fmul_rn(trj[pt * 2 + 1], 1.25f), 160.0f);
    float x0 = ceilf(__fadd_rn(cx, -3.0f));
    float y0 = ceilf(__fadd_rn(cy, -3.0f));

    float wx[6], wy[6];
    int ix[6], iy[6];
    #pragma unroll
    for (int d = 0; d < 6; d++) {
        float px = x0 + (float)d;
        float u = __fdiv_rn(__fsub_rn(px, cx), 3.0f);
        wx[d] = i0f(BETA_F * sqrtf(fmaxf(1.0f - u * u, 0.0f)));
        int v = (int)px;
        ix[d] = ((v % OSN) + OSN) % OSN;

        float py = y0 + (float)d;
        float w = __fdiv_rn(__fsub_rn(py, cy), 3.0f);
        wy[d] = i0f(BETA_F * sqrtf(fmaxf(1.0f - w * w, 0.0f)));
        int vy = (int)py;
        iy[d] = ((vy % OSN) + OSN) % OSN;
    }

    float accRe = 0.f, accIm = 0.f;
    #pragma unroll
    for (int dx = 0; dx < 6; dx++) {
        long base = (long)ix[dx] * OSN;
        #pragma unroll
        for (int dy = 0; dy < 6; dy++) {
            long gidx = (base + iy[dy]) * NCH + c;
            float2 g = grid[gidx];
            float w = wx[dx] * wy[dy];
            accRe += g.x * w;
            accIm += g.y * w;
        }
    }
    accRe *= (1.0f / 36.0f);
    accIm *= (1.0f / 36.0f);

    __shared__ float2 lds[256];
    lds[t] = make_float2(accRe, accIm);
    __syncthreads();
    int c2 = t >> 5, p2 = t & 31;
    float2 v = lds[p2 * 8 + c2];
    // PAIR SWAP: element 2e = imag, element 2e+1 = real
    out[(long)c2 * NPTS + blockIdx.x * 32 + p2] = f2bf(v.y) | (f2bf(v.x) << 16);
}

extern "C" void kernel_launch(void* const* d_in, const int* in_sizes, int n_in,
                              void* d_out, int out_size, void* d_ws, size_t ws_size,
                              hipStream_t stream) {
    const float* img_r = (const float*)d_in[0];   // fp32 (R4)
    const float* img_i = (const float*)d_in[1];   // fp32
    const float* trj   = (const float*)d_in[2];   // fp32 (R12)

    // Memory plan: d_out: R1 @ 0 (6,553,600 B), W @ 6,553,600 (819,200 B);
    // d_ws: xp @ 0, then G overwrites xp once dead. All buffers fully
    // rewritten every call (graph-replay safe).
    char* ob = (char*)d_out;
    float2* R1 = (float2*)(ob);
    float2* W  = (float2*)(ob + 6553600);
    float2* xp = (float2*)d_ws;
    float2* G  = (float2*)d_ws;

    build_w <<<(OSN * OSN + 255) / 256, 256, 0, stream>>>(W);
    build_xp<<<(NCH * OSN * OSN) / 256, 256, 0, stream>>>(img_r, img_i, xp);
    dft_rows<<<(NCH * OSN * OSN) / 256, 256, 0, stream>>>(xp, W, R1);
    dft_cols<<<(NCH * OSN * OSN) / 256, 256, 0, stream>>>(R1, W, G);
    interp_kernel<<<NPTS / 32, 256, 0, stream>>>(trj, G, (u32*)d_out);
}

// Round 14
// 286.245 us; speedup vs baseline: 2.1500x; 2.1500x over previous
//
#include <hip/hip_runtime.h>
#include <math.h>

// ---- problem constants ----
#define NCH   8
#define IMN   256
#define OSN   320
#define NPTS  (64*4096)            // 262144 trajectory points
#define BETA_F   10.9551078f       // pi*sqrt((6/1.25*0.75)^2 - 0.8)
#define BETA2_F  120.014389f       // BETA^2
#define APOD_C   0.05890486225f    // pi*WIDTH/OSN = pi*6/320

typedef unsigned int u32;

// float -> bf16 bits, round-to-nearest-even
__device__ __forceinline__ u32 f2bf(float f) {
    u32 u = __float_as_uint(f);
    return (u + 0x7FFFu + ((u >> 16) & 1u)) >> 16;
}

// Kaiser-Bessel i0 (Abramowitz & Stegun 9.8.1 / 9.8.2), rel err ~5e-7
__device__ __forceinline__ float i0f(float t) {
    if (t < 3.75f) {
        float y = t * t * (1.0f / 14.0625f);
        return 1.0f + y * (3.5156229f + y * (3.0899424f + y * (1.2067492f +
                     y * (0.2659732f + y * (0.0360768f + y * 0.0045813f)))));
    }
    float z = 3.75f / t;
    float p = 0.39894228f + z * (0.01328592f + z * (0.00225319f + z * (-0.00157565f +
              z * (0.00916281f + z * (-0.02057706f + z * (0.02635537f +
              z * (-0.01647633f + z * 0.00392377f)))))));
    return expf(t) * rsqrtf(t) * p;
}

__device__ __forceinline__ float apodf(int i) {
    float x = APOD_C * (float)(i - IMN / 2);
    float arg = sqrtf(BETA2_F - x * x);
    float e = expf(arg);
    float sh = 0.5f * (e - 1.0f / e);
    return arg / sh;
}

// M2[k][j] = (-1)^(k+j) * exp(-2*pi*i*k*(j+32)/320), 320x256 row-major.
// Folded centered-FFT-with-pad matrix. R3/R6/R9 proved this produces values
// BIT-IDENTICAL to the literal shift/pad/DFT pipeline (6.78125 x3).
__global__ void build_m2(float2* __restrict__ m2) {
    int idx = blockIdx.x * 256 + threadIdx.x;
    if (idx >= OSN * IMN) return;
    int k = idx / IMN, j = idx - k * IMN;
    int p = (k * (j + 32)) % OSN;
    float th = (2.0f * (float)M_PI / (float)OSN) * (float)p;
    float s = ((k + j) & 1) ? -1.0f : 1.0f;
    float sn, cs;
    sincosf(th, &sn, &cs);
    m2[idx] = make_float2(s * cs, -s * sn);
}

// GEMM1: T[c][i1][k2] = sum_i2 (img*apod(i1)*apod(i2)/256)[c][i1][i2] * M2[k2][i2]
// M=256 (i1), N=320 (k2), K=256 (i2). grid (5,4,8), 64x64 tile, 4x4/thread.
__launch_bounds__(256)
__global__ void gemm1(const float* __restrict__ img_r, const float* __restrict__ img_i,
                      const float2* __restrict__ M2, float2* __restrict__ T) {
    const int c = blockIdx.z;
    const int rowBase = blockIdx.y * 64;     // i1
    const int colBase = blockIdx.x * 64;     // k2
    __shared__ float2 As[16][65];
    __shared__ float2 Bs[16][65];
    __shared__ float apc[256];
    const int t = threadIdx.x;
    apc[t] = apodf(t) * (1.0f / 256.0f);
    const int tx = t & 15, ty = t >> 4;
    const int lr = t >> 2, lk0 = (t & 3) * 4;
    const float ar = apodf(rowBase + lr);
    float cRe[4][4] = {{0.f}}, cIm[4][4] = {{0.f}};
    __syncthreads();                         // apc ready

    for (int kt = 0; kt < 256; kt += 16) {
        {   // A tile with fused apodization (fp32 inputs)
            long base = ((long)(c * IMN + rowBase + lr)) * IMN + kt + lk0;
            float4 vr = *(const float4*)(img_r + base);
            float4 vi = *(const float4*)(img_i + base);
            float w0 = ar * apc[kt + lk0 + 0];
            float w1 = ar * apc[kt + lk0 + 1];
            float w2 = ar * apc[kt + lk0 + 2];
            float w3 = ar * apc[kt + lk0 + 3];
            As[lk0 + 0][lr] = make_float2(vr.x * w0, vi.x * w0);
            As[lk0 + 1][lr] = make_float2(vr.y * w1, vi.y * w1);
            As[lk0 + 2][lr] = make_float2(vr.z * w2, vi.z * w2);
            As[lk0 + 3][lr] = make_float2(vr.w * w3, vi.w * w3);
        }
        {   // B tile: M2 is N x K row-major (B^T)
            const float2* bp = M2 + (long)(colBase + lr) * IMN + kt + lk0;
            #pragma unroll
            for (int i = 0; i < 4; i++) Bs[lk0 + i][lr] = bp[i];
        }
        __syncthreads();
        #pragma unroll
        for (int kk = 0; kk < 16; kk++) {
            float2 a[4], b[4];
            #pragma unroll
            for (int i = 0; i < 4; i++) a[i] = As[kk][ty * 4 + i];
            #pragma unroll
            for (int j = 0; j < 4; j++) b[j] = Bs[kk][tx * 4 + j];
            #pragma unroll
            for (int i = 0; i < 4; i++)
                #pragma unroll
                for (int j = 0; j < 4; j++) {
                    cRe[i][j] += a[i].x * b[j].x - a[i].y * b[j].y;
                    cIm[i][j] += a[i].x * b[j].y + a[i].y * b[j].x;
                }
        }
        __syncthreads();
    }
    #pragma unroll
    for (int i = 0; i < 4; i++)
        #pragma unroll
        for (int j = 0; j < 4; j++) {
            long off = (long)c * IMN * OSN + (long)(rowBase + ty * 4 + i) * OSN
                     + colBase + tx * 4 + j;
            T[off] = make_float2(cRe[i][j], cIm[i][j]);
        }
}

// GEMM2: G[k1][k2][c] = sum_i1 M2[k1][i1] * T[c][i1][k2]
// M=320 (k1), N=320 (k2), K=256 (i1). grid (5,5,8). G interleaved (k1,k2,c).
__launch_bounds__(256)
__global__ void gemm2(const float2* __restrict__ M2, const float2* __restrict__ T,
                      float2* __restrict__ G) {
    const int c = blockIdx.z;
    const int rowBase = blockIdx.y * 64;     // k1
    const int colBase = blockIdx.x * 64;     // k2
    __shared__ float2 As[16][65];
    __shared__ float2 Bs[16][65];
    const int t = threadIdx.x;
    const int tx = t & 15, ty = t >> 4;
    const int lr = t >> 2, lk0 = (t & 3) * 4;
    float cRe[4][4] = {{0.f}}, cIm[4][4] = {{0.f}};

    for (int kt = 0; kt < 256; kt += 16) {
        {   // A tile: M2 row-major M x K
            const float2* ap = M2 + (long)(rowBase + lr) * IMN + kt + lk0;
            #pragma unroll
            for (int i = 0; i < 4; i++) As[lk0 + i][lr] = ap[i];
        }
        {   // B tile: T[c] is K x N row-major
            const int kk = t >> 4, n0 = (t & 15) * 4;
            const float2* bp = T + (long)c * IMN * OSN + (long)(kt + kk) * OSN
                             + colBase + n0;
            #pragma unroll
            for (int i = 0; i < 4; i++) Bs[kk][n0 + i] = bp[i];
        }
        __syncthreads();
        #pragma unroll
        for (int kk = 0; kk < 16; kk++) {
            float2 a[4], b[4];
            #pragma unroll
            for (int i = 0; i < 4; i++) a[i] = As[kk][ty * 4 + i];
            #pragma unroll
            for (int j = 0; j < 4; j++) b[j] = Bs[kk][tx * 4 + j];
            #pragma unroll
            for (int i = 0; i < 4; i++)
                #pragma unroll
                for (int j = 0; j < 4; j++) {
                    cRe[i][j] += a[i].x * b[j].x - a[i].y * b[j].y;
                    cIm[i][j] += a[i].x * b[j].y + a[i].y * b[j].x;
                }
        }
        __syncthreads();
    }
    #pragma unroll
    for (int i = 0; i < 4; i++)
        #pragma unroll
        for (int j = 0; j < 4; j++) {
            long off = ((long)(rowBase + ty * 4 + i) * OSN + colBase + tx * 4 + j) * NCH + c;
            G[off] = make_float2(cRe[i][j], cIm[i][j]);
        }
}

// KB interpolation (GREEN in R13). Grid (k1,k2,c) interleaved; comp 0 -> k1.
// Output pack: element 2e = IMAG, 2e+1 = REAL (the i*conj convention).
__global__ void interp_kernel(const float* __restrict__ trj,
                              const float2* __restrict__ grid,
                              u32* __restrict__ out) {
    const int t = threadIdx.x;
    const int c = t & 7;
    const int pl = t >> 3;
    const int pt = blockIdx.x * 32 + pl;

    float cx = __fadd_rn(__fmul_rn(trj[pt * 2 + 0], 1.25f), 160.0f);
    float cy = __fadd_rn(__fmul_rn(trj[pt * 2 + 1], 1.25f), 160.0f);
    float x0 = ceilf(__fadd_rn(cx, -3.0f));
    float y0 = ceilf(__fadd_rn(cy, -3.0f));

    float wx[6], wy[6];
    int ix[6], iy[6];
    #pragma unroll
    for (int d = 0; d < 6; d++) {
        float px = x0 + (float)d;
        float u = __fdiv_rn(__fsub_rn(px, cx), 3.0f);
        wx[d] = i0f(BETA_F * sqrtf(fmaxf(1.0f - u * u, 0.0f)));
        int v = (int)px;
        ix[d] = ((v % OSN) + OSN) % OSN;

        float py = y0 + (float)d;
        float w = __fdiv_rn(__fsub_rn(py, cy), 3.0f);
        wy[d] = i0f(BETA_F * sqrtf(fmaxf(1.0f - w * w, 0.0f)));
        int vy = (int)py;
        iy[d] = ((vy % OSN) + OSN) % OSN;
    }

    float accRe = 0.f, accIm = 0.f;
    #pragma unroll
    for (int dx = 0; dx < 6; dx++) {
        long base = (long)ix[dx] * OSN;
        #pragma unroll
        for (int dy = 0; dy < 6; dy++) {
            long gidx = (base + iy[dy]) * NCH + c;
            float2 g = grid[gidx];
            float w = wx[dx] * wy[dy];
            accRe += g.x * w;
            accIm += g.y * w;
        }
    }
    accRe *= (1.0f / 36.0f);
    accIm *= (1.0f / 36.0f);

    __shared__ float2 lds[256];
    lds[t] = make_float2(accRe, accIm);
    __syncthreads();
    int c2 = t >> 5, p2 = t & 31;
    float2 v = lds[p2 * 8 + c2];
    // (imag, real) pack — verified green R13
    out[(long)c2 * NPTS + blockIdx.x * 32 + p2] = f2bf(v.y) | (f2bf(v.x) << 16);
}

extern "C" void kernel_launch(void* const* d_in, const int* in_sizes, int n_in,
                              void* d_out, int out_size, void* d_ws, size_t ws_size,
                              hipStream_t stream) {
    const float* img_r = (const float*)d_in[0];
    const float* img_i = (const float*)d_in[1];
    const float* trj   = (const float*)d_in[2];

    // Memory plan (proven safe R3..R13): d_out (8,388,608 B) hosts
    // T @ 0 (5,242,880 B) + M2 @ 5,242,880 (655,360 B); both dead before
    // interp overwrites all of d_out. d_ws hosts G (6,553,600 B).
    char* ob = (char*)d_out;
    float2* T  = (float2*)(ob);
    float2* M2 = (float2*)(ob + 5242880);
    float2* G  = (float2*)d_ws;

    build_m2<<<(OSN * IMN + 255) / 256, 256, 0, stream>>>(M2);
    gemm1<<<dim3(OSN / 64, IMN / 64, NCH), 256, 0, stream>>>(img_r, img_i, M2, T);
    gemm2<<<dim3(OSN / 64, OSN / 64, NCH), 256, 0, stream>>>(M2, T, G);
    interp_kernel<<<NPTS / 32, 256, 0, stream>>>(trj, G, (u32*)d_out);
}

// Round 15
// 210.143 us; speedup vs baseline: 2.9286x; 1.3621x over previous
//
#include <hip/hip_runtime.h>
#include <math.h>

// ---- problem constants ----
#define NCH   8
#define IMN   256
#define OSN   320
#define NPTS  (64*4096)            // 262144 trajectory points
#define BETA_F   10.9551078f       // pi*sqrt((6/1.25*0.75)^2 - 0.8)
#define BETA2_F  120.014389f       // BETA^2
#define APOD_C   0.05890486225f    // pi*WIDTH/OSN = pi*6/320

typedef unsigned int u32;

__device__ __forceinline__ u32 f2bf(float f) {
    u32 u = __float_as_uint(f);
    return (u + 0x7FFFu + ((u >> 16) & 1u)) >> 16;
}

// Kaiser-Bessel i0 (Abramowitz & Stegun), rel err ~5e-7
__device__ __forceinline__ float i0f(float t) {
    if (t < 3.75f) {
        float y = t * t * (1.0f / 14.0625f);
        return 1.0f + y * (3.5156229f + y * (3.0899424f + y * (1.2067492f +
                     y * (0.2659732f + y * (0.0360768f + y * 0.0045813f)))));
    }
    float z = 3.75f / t;
    float p = 0.39894228f + z * (0.01328592f + z * (0.00225319f + z * (-0.00157565f +
              z * (0.00916281f + z * (-0.02057706f + z * (0.02635537f +
              z * (-0.01647633f + z * 0.00392377f)))))));
    return expf(t) * rsqrtf(t) * p;
}

__device__ __forceinline__ float apodf(int i) {
    float x = APOD_C * (float)(i - IMN / 2);
    float arg = sqrtf(BETA2_F - x * x);
    float e = expf(arg);
    float sh = 0.5f * (e - 1.0f / e);
    return arg / sh;
}

// M2[k][j] = (-1)^(k+j) * exp(-2*pi*i*k*(j+32)/320), 320x256 row-major.
__global__ void build_m2(float2* __restrict__ m2) {
    int idx = blockIdx.x * 256 + threadIdx.x;
    if (idx >= OSN * IMN) return;
    int k = idx / IMN, j = idx - k * IMN;
    int p = (k * (j + 32)) % OSN;
    float th = (2.0f * (float)M_PI / (float)OSN) * (float)p;
    float s = ((k + j) & 1) ? -1.0f : 1.0f;
    float sn, cs;
    sincosf(th, &sn, &cs);
    m2[idx] = make_float2(s * cs, -s * sn);
}

// GEMM1: T[c][i1][k2] = sum_i2 (img*apod(i1)*apod(i2)/256)[c][i1][i2] * M2[k2][i2]
// 32x32 tiles, 2x2/thread. grid (10,8,8)=640 blocks (occupancy fix vs 64-tile).
__launch_bounds__(256)
__global__ void gemm1(const float* __restrict__ img_r, const float* __restrict__ img_i,
                      const float2* __restrict__ M2, float2* __restrict__ T) {
    const int c = blockIdx.z;
    const int rowBase = blockIdx.y * 32;     // i1
    const int colBase = blockIdx.x * 32;     // k2
    __shared__ float2 As[16][34];            // [k][row], stride 34 (even: float4-aligned)
    __shared__ float2 Bs[16][34];            // [k][col]
    __shared__ float apc[256];
    const int t = threadIdx.x;
    apc[t] = apodf(t) * (1.0f / 256.0f);
    const int tx = t & 15, ty = t >> 4;
    const int lrow = t >> 3;                 // load row/col 0..31
    const int lk = (t & 7) * 2;              // load k 0,2,..,14
    const float ar = apodf(rowBase + lrow);  // same factorization as R14 (bit-exact)
    float cRe[2][2] = {{0.f}}, cIm[2][2] = {{0.f}};
    __syncthreads();                         // apc ready

    for (int kt = 0; kt < 256; kt += 16) {
        {   // A tile: img row lrow, k pair lk (fused apodization)
            long base = ((long)(c * IMN + rowBase + lrow)) * IMN + kt + lk;
            float2 vr = *(const float2*)(img_r + base);
            float2 vi = *(const float2*)(img_i + base);
            float w0 = ar * apc[kt + lk + 0];
            float w1 = ar * apc[kt + lk + 1];
            As[lk + 0][lrow] = make_float2(vr.x * w0, vi.x * w0);
            As[lk + 1][lrow] = make_float2(vr.y * w1, vi.y * w1);
        }
        {   // B tile: M2 is N x K row-major (B^T); 2 consecutive k = float4
            float4 bv = *(const float4*)(M2 + (long)(colBase + lrow) * IMN + kt + lk);
            Bs[lk + 0][lrow] = make_float2(bv.x, bv.y);
            Bs[lk + 1][lrow] = make_float2(bv.z, bv.w);
        }
        __syncthreads();
        #pragma unroll
        for (int kk = 0; kk < 16; kk++) {
            float4 av = *(const float4*)&As[kk][ty * 2];   // 2 float2, 16B aligned
            float4 bv = *(const float4*)&Bs[kk][tx * 2];
            float2 a[2] = {{av.x, av.y}, {av.z, av.w}};
            float2 b[2] = {{bv.x, bv.y}, {bv.z, bv.w}};
            #pragma unroll
            for (int i = 0; i < 2; i++)
                #pragma unroll
                for (int j = 0; j < 2; j++) {
                    cRe[i][j] += a[i].x * b[j].x - a[i].y * b[j].y;
                    cIm[i][j] += a[i].x * b[j].y + a[i].y * b[j].x;
                }
        }
        __syncthreads();
    }
    #pragma unroll
    for (int i = 0; i < 2; i++) {
        long off = (long)c * IMN * OSN + (long)(rowBase + ty * 2 + i) * OSN
                 + colBase + tx * 2;
        float4 ov = make_float4(cRe[i][0], cIm[i][0], cRe[i][1], cIm[i][1]);
        *(float4*)(T + off) = ov;            // 2 consecutive k2: 16B store
    }
}

// GEMM2: G[k1][k2][c] = sum_i1 M2[k1][i1] * T[c][i1][k2]
// 32x32 tiles, 2x2/thread. grid (10,10,8)=800 blocks.
__launch_bounds__(256)
__global__ void gemm2(const float2* __restrict__ M2, const float2* __restrict__ T,
                      float2* __restrict__ G) {
    const int c = blockIdx.z;
    const int rowBase = blockIdx.y * 32;     // k1
    const int colBase = blockIdx.x * 32;     // k2
    __shared__ float2 As[16][34];
    __shared__ float2 Bs[16][34];
    const int t = threadIdx.x;
    const int tx = t & 15, ty = t >> 4;
    const int lrow = t >> 3, lk = (t & 7) * 2;
    const int lkk = t >> 4, ln0 = (t & 15) * 2;
    float cRe[2][2] = {{0.f}}, cIm[2][2] = {{0.f}};

    for (int kt = 0; kt < 256; kt += 16) {
        {   // A tile: M2 row-major M x K; 2 consecutive k = float4
            float4 av = *(const float4*)(M2 + (long)(rowBase + lrow) * IMN + kt + lk);
            As[lk + 0][lrow] = make_float2(av.x, av.y);
            As[lk + 1][lrow] = make_float2(av.z, av.w);
        }
        {   // B tile: T[c] K x N row-major; 2 consecutive n = float4 both ways
            float4 bv = *(const float4*)(T + (long)c * IMN * OSN
                         + (long)(kt + lkk) * OSN + colBase + ln0);
            *(float4*)&Bs[lkk][ln0] = bv;
        }
        __syncthreads();
        #pragma unroll
        for (int kk = 0; kk < 16; kk++) {
            float4 av = *(const float4*)&As[kk][ty * 2];
            float4 bv = *(const float4*)&Bs[kk][tx * 2];
            float2 a[2] = {{av.x, av.y}, {av.z, av.w}};
            float2 b[2] = {{bv.x, bv.y}, {bv.z, bv.w}};
            #pragma unroll
            for (int i = 0; i < 2; i++)
                #pragma unroll
                for (int j = 0; j < 2; j++) {
                    cRe[i][j] += a[i].x * b[j].x - a[i].y * b[j].y;
                    cIm[i][j] += a[i].x * b[j].y + a[i].y * b[j].x;
                }
        }
        __syncthreads();
    }
    #pragma unroll
    for (int i = 0; i < 2; i++)
        #pragma unroll
        for (int j = 0; j < 2; j++) {
            long off = ((long)(rowBase + ty * 2 + i) * OSN + colBase + tx * 2 + j) * NCH + c;
            G[off] = make_float2(cRe[i][j], cIm[i][j]);
        }
}

// KB interpolation (GREEN R13 conventions). Weight hoisting: only threads
// t<32 (half of wave 0) compute the 12 i0f per point; waves 1-3 skip all
// transcendentals. Same products/order -> bit-identical accumulation.
// Output pack: element 2e = IMAG, 2e+1 = REAL (i*conj convention).
__global__ void interp_kernel(const float* __restrict__ trj,
                              const float2* __restrict__ grid,
                              u32* __restrict__ out) {
    const int t = threadIdx.x;
    const int c = t & 7;
    const int pl = t >> 3;                   // local point 0..31
    __shared__ float wxs[32][6], wys[32][6];
    __shared__ int   x0s[32], y0s[32];

    if (t < 32) {                            // one weight-computer per point
        int pt = blockIdx.x * 32 + t;
        float2 tv = *(const float2*)(trj + pt * 2);
        float cx = __fadd_rn(__fmul_rn(tv.x, 1.25f), 160.0f);
        float cy = __fadd_rn(__fmul_rn(tv.y, 1.25f), 160.0f);
        float x0 = ceilf(__fadd_rn(cx, -3.0f));
        float y0 = ceilf(__fadd_rn(cy, -3.0f));
        x0s[t] = (int)x0;
        y0s[t] = (int)y0;
        #pragma unroll
        for (int d = 0; d < 6; d++) {
            float u = __fdiv_rn(__fsub_rn(x0 + (float)d, cx), 3.0f);
            wxs[t][d] = i0f(BETA_F * sqrtf(fmaxf(1.0f - u * u, 0.0f)));
            float w = __fdiv_rn(__fsub_rn(y0 + (float)d, cy), 3.0f);
            wys[t][d] = i0f(BETA_F * sqrtf(fmaxf(1.0f - w * w, 0.0f)));
        }
    }
    __syncthreads();

    int ix[6], iy[6];
    const int x0i = x0s[pl], y0i = y0s[pl];
    #pragma unroll
    for (int d = 0; d < 6; d++) {
        int vx = x0i + d;
        ix[d] = ((vx % OSN) + OSN) % OSN;
        int vy = y0i + d;
        iy[d] = ((vy % OSN) + OSN) % OSN;
    }

    float accRe = 0.f, accIm = 0.f;
    #pragma unroll
    for (int dx = 0; dx < 6; dx++) {
        long base = (long)ix[dx] * OSN;
        float wxv = wxs[pl][dx];
        #pragma unroll
        for (int dy = 0; dy < 6; dy++) {
            long gidx = (base + iy[dy]) * NCH + c;
            float2 g = grid[gidx];
            float w = wxv * wys[pl][dy];
            accRe += g.x * w;
            accIm += g.y * w;
        }
    }
    accRe *= (1.0f / 36.0f);
    accIm *= (1.0f / 36.0f);

    __shared__ float2 lds[256];
    lds[t] = make_float2(accRe, accIm);
    __syncthreads();
    int c2 = t >> 5, p2 = t & 31;
    float2 v = lds[p2 * 8 + c2];
    // (imag, real) pack — verified green R13
    out[(long)c2 * NPTS + blockIdx.x * 32 + p2] = f2bf(v.y) | (f2bf(v.x) << 16);
}

extern "C" void kernel_launch(void* const* d_in, const int* in_sizes, int n_in,
                              void* d_out, int out_size, void* d_ws, size_t ws_size,
                              hipStream_t stream) {
    const float* img_r = (const float*)d_in[0];
    const float* img_i = (const float*)d_in[1];
    const float* trj   = (const float*)d_in[2];

    // Memory plan (proven safe): d_out (8,388,608 B) hosts T @ 0 (5,242,880 B)
    // + M2 @ 5,242,880 (655,360 B); both dead before interp overwrites d_out.
    // d_ws hosts G (6,553,600 B).
    char* ob = (char*)d_out;
    float2* T  = (float2*)(ob);
    float2* M2 = (float2*)(ob + 5242880);
    float2* G  = (float2*)d_ws;

    build_m2<<<(OSN * IMN + 255) / 256, 256, 0, stream>>>(M2);
    gemm1<<<dim3(OSN / 32, IMN / 32, NCH), 256, 0, stream>>>(img_r, img_i, M2, T);
    gemm2<<<dim3(OSN / 32, OSN / 32, NCH), 256, 0, stream>>>(M2, T, G);
    interp_kernel<<<NPTS / 32, 256, 0, stream>>>(trj, G, (u32*)d_out);
}

// Round 16
// 146.475 us; speedup vs baseline: 4.2016x; 1.4347x over previous
//
#include <hip/hip_runtime.h>
#include <math.h>

// ---- problem constants ----
#define NCH   8
#define IMN   256
#define OSN   320
#define NPTS  (64*4096)            // 262144 trajectory points
#define KD    512                  // doubled K (re,im interleaved)
#define BETA_F   10.9551078f
#define BETA2_F  120.014389f
#define APOD_C   0.05890486225f    // pi*6/320

typedef unsigned short u16;
typedef unsigned int   u32;
typedef __attribute__((ext_vector_type(8))) short s16x8;   // 8 bf16 (4 VGPRs)
typedef __attribute__((ext_vector_type(4))) float f32x4;   // MFMA acc

__device__ __forceinline__ u32 f2bf(float f) {
    u32 u = __float_as_uint(f);
    return (u + 0x7FFFu + ((u >> 16) & 1u)) >> 16;
}

// Kaiser-Bessel i0 (A&S), rel err ~5e-7
__device__ __forceinline__ float i0f(float t) {
    if (t < 3.75f) {
        float y = t * t * (1.0f / 14.0625f);
        return 1.0f + y * (3.5156229f + y * (3.0899424f + y * (1.2067492f +
                     y * (0.2659732f + y * (0.0360768f + y * 0.0045813f)))));
    }
    float z = 3.75f / t;
    float p = 0.39894228f + z * (0.01328592f + z * (0.00225319f + z * (-0.00157565f +
              z * (0.00916281f + z * (-0.02057706f + z * (0.02635537f +
              z * (-0.01647633f + z * 0.00392377f)))))));
    return expf(t) * rsqrtf(t) * p;
}

__device__ __forceinline__ float apodf(int i) {
    float x = APOD_C * (float)(i - IMN / 2);
    float arg = sqrtf(BETA2_F - x * x);
    float e = expf(arg);
    float sh = 0.5f * (e - 1.0f / e);
    return arg / sh;
}

// B1[k][kd] = interleave(M2re[k][:], -M2im[k][:]);  B2 = interleave(M2im, M2re)
// M2[k][j] = (-1)^(k+j) e^{-2pi i k(j+32)/320}  (verified R9/R13 green base)
__global__ void prep_const(u32* __restrict__ B1, u32* __restrict__ B2) {
    int idx = blockIdx.x * 256 + threadIdx.x;   // 320*256
    int k = idx >> 8, j = idx & 255;
    int p = (k * (j + 32)) % OSN;
    float th = (2.0f * (float)M_PI / (float)OSN) * (float)p;
    float s = ((k + j) & 1) ? -1.0f : 1.0f;
    float sn, cs;
    sincosf(th, &sn, &cs);
    float re = s * cs, im = -s * sn;
    B1[idx] = f2bf(re) | (f2bf(-im) << 16);
    B2[idx] = f2bf(im) | (f2bf(re) << 16);
}

// Abf[c][i1][kd]: apodized complex image, bf16, (re,im) interleaved along kd
__global__ void prep_a(const float* __restrict__ r, const float* __restrict__ im,
                       u32* __restrict__ A) {
    int idx = blockIdx.x * 256 + threadIdx.x;   // 8*256*256
    int i2 = idx & 255, i1 = (idx >> 8) & 255;
    float w = apodf(i1) * apodf(i2) * (1.0f / 256.0f);
    A[idx] = f2bf(r[idx] * w) | (f2bf(im[idx] * w) << 16);
}

// GEMM1 (MFMA): T[c][i1][k2] = sum_i2 Aimg[i1][i2]*M2[k2][i2]  (complex)
// Real form: Tre = sum_kd Abf*B1[k2], Tim = sum_kd Abf*B2[k2].
// Out Tb[c][k2][kd] bf16, kd = (2*i1 | 2*i1+1) -> K-contiguous for gemm2.
__launch_bounds__(256)
__global__ void gemm1(const short* __restrict__ Abf, const short* __restrict__ B1,
                      const short* __restrict__ B2, short* __restrict__ Tb) {
    const int c = blockIdx.z;
    const int mBase = blockIdx.y * 64;   // i1
    const int nBase = blockIdx.x * 64;   // k2
    __shared__ short As[64][40], B1s[64][40], B2s[64][40];  // stride 40: conflict-free
    const int t = threadIdx.x;
    const int l = t & 63, w = t >> 6;
    const int wy = w >> 1, wx = w & 1;
    const int row = t >> 2, seg = (t & 3) * 8;
    const int fm = l & 15, fq = (l >> 4) * 8;
    f32x4 zz = {0.f, 0.f, 0.f, 0.f};
    f32x4 accRe[2][2], accIm[2][2];
    #pragma unroll
    for (int i = 0; i < 2; i++)
        #pragma unroll
        for (int j = 0; j < 2; j++) { accRe[i][j] = zz; accIm[i][j] = zz; }

    for (int kc = 0; kc < 16; kc++) {
        const int kb = kc * 32 + seg;
        *(s16x8*)&As [row][seg] = *(const s16x8*)(Abf + ((long)(c * IMN + mBase + row)) * KD + kb);
        *(s16x8*)&B1s[row][seg] = *(const s16x8*)(B1 + (long)(nBase + row) * KD + kb);
        *(s16x8*)&B2s[row][seg] = *(const s16x8*)(B2 + (long)(nBase + row) * KD + kb);
        __syncthreads();
        s16x8 a0  = *(const s16x8*)&As [wy * 32 + fm][fq];
        s16x8 a1  = *(const s16x8*)&As [wy * 32 + 16 + fm][fq];
        s16x8 b10 = *(const s16x8*)&B1s[wx * 32 + fm][fq];
        s16x8 b11 = *(const s16x8*)&B1s[wx * 32 + 16 + fm][fq];
        s16x8 b20 = *(const s16x8*)&B2s[wx * 32 + fm][fq];
        s16x8 b21 = *(const s16x8*)&B2s[wx * 32 + 16 + fm][fq];
        accRe[0][0] = __builtin_amdgcn_mfma_f32_16x16x32_bf16(a0, b10, accRe[0][0], 0, 0, 0);
        accRe[0][1] = __builtin_amdgcn_mfma_f32_16x16x32_bf16(a0, b11, accRe[0][1], 0, 0, 0);
        accRe[1][0] = __builtin_amdgcn_mfma_f32_16x16x32_bf16(a1, b10, accRe[1][0], 0, 0, 0);
        accRe[1][1] = __builtin_amdgcn_mfma_f32_16x16x32_bf16(a1, b11, accRe[1][1], 0, 0, 0);
        accIm[0][0] = __builtin_amdgcn_mfma_f32_16x16x32_bf16(a0, b20, accIm[0][0], 0, 0, 0);
        accIm[0][1] = __builtin_amdgcn_mfma_f32_16x16x32_bf16(a0, b21, accIm[0][1], 0, 0, 0);
        accIm[1][0] = __builtin_amdgcn_mfma_f32_16x16x32_bf16(a1, b20, accIm[1][0], 0, 0, 0);
        accIm[1][1] = __builtin_amdgcn_mfma_f32_16x16x32_bf16(a1, b21, accIm[1][1], 0, 0, 0);
        __syncthreads();
    }
    // C/D layout (verified m89/m91): col = lane&15, row = (lane>>4)*4 + reg
    #pragma unroll
    for (int i = 0; i < 2; i++)
        #pragma unroll
        for (int j = 0; j < 2; j++) {
            int i1b = mBase + wy * 32 + i * 16 + (l >> 4) * 4;   // 4-aligned i1 base
            int k2  = nBase + wx * 32 + j * 16 + fm;
            s16x8 v;
            #pragma unroll
            for (int r = 0; r < 4; r++) {
                v[2 * r]     = (short)f2bf(accRe[i][j][r]);
                v[2 * r + 1] = (short)f2bf(accIm[i][j][r]);
            }
            *(s16x8*)(Tb + ((long)(c * OSN + k2)) * KD + 2 * i1b) = v;
        }
}

// GEMM2 (MFMA): G[k1][k2][c] = sum_i1 M2[k1][i1]*T[i1][k2]
// Gre = sum_kd B1[k1]*Tb[k2], Gim = sum_kd B2[k1]*Tb[k2]. G stays fp32.
__launch_bounds__(256)
__global__ void gemm2(const short* __restrict__ B1, const short* __restrict__ B2,
                      const short* __restrict__ Tb, float2* __restrict__ G) {
    const int c = blockIdx.z;
    const int mBase = blockIdx.y * 64;   // k1
    const int nBase = blockIdx.x * 64;   // k2
    __shared__ short A1s[64][40], A2s[64][40], Bs[64][40];
    const int t = threadIdx.x;
    const int l = t & 63, w = t >> 6;
    const int wy = w >> 1, wx = w & 1;
    const int row = t >> 2, seg = (t & 3) * 8;
    const int fm = l & 15, fq = (l >> 4) * 8;
    f32x4 zz = {0.f, 0.f, 0.f, 0.f};
    f32x4 accRe[2][2], accIm[2][2];
    #pragma unroll
    for (int i = 0; i < 2; i++)
        #pragma unroll
        for (int j = 0; j < 2; j++) { accRe[i][j] = zz; accIm[i][j] = zz; }

    for (int kc = 0; kc < 16; kc++) {
        const int kb = kc * 32 + seg;
        *(s16x8*)&A1s[row][seg] = *(const s16x8*)(B1 + (long)(mBase + row) * KD + kb);
        *(s16x8*)&A2s[row][seg] = *(const s16x8*)(B2 + (long)(mBase + row) * KD + kb);
        *(s16x8*)&Bs [row][seg] = *(const s16x8*)(Tb + ((long)(c * OSN + nBase + row)) * KD + kb);
        __syncthreads();
        s16x8 a10 = *(const s16x8*)&A1s[wy * 32 + fm][fq];
        s16x8 a11 = *(const s16x8*)&A1s[wy * 32 + 16 + fm][fq];
        s16x8 a20 = *(const s16x8*)&A2s[wy * 32 + fm][fq];
        s16x8 a21 = *(const s16x8*)&A2s[wy * 32 + 16 + fm][fq];
        s16x8 b0  = *(const s16x8*)&Bs [wx * 32 + fm][fq];
        s16x8 b1  = *(const s16x8*)&Bs [wx * 32 + 16 + fm][fq];
        accRe[0][0] = __builtin_amdgcn_mfma_f32_16x16x32_bf16(a10, b0, accRe[0][0], 0, 0, 0);
        accRe[0][1] = __builtin_amdgcn_mfma_f32_16x16x32_bf16(a10, b1, accRe[0][1], 0, 0, 0);
        accRe[1][0] = __builtin_amdgcn_mfma_f32_16x16x32_bf16(a11, b0, accRe[1][0], 0, 0, 0);
        accRe[1][1] = __builtin_amdgcn_mfma_f32_16x16x32_bf16(a11, b1, accRe[1][1], 0, 0, 0);
        accIm[0][0] = __builtin_amdgcn_mfma_f32_16x16x32_bf16(a20, b0, accIm[0][0], 0, 0, 0);
        accIm[0][1] = __builtin_amdgcn_mfma_f32_16x16x32_bf16(a20, b1, accIm[0][1], 0, 0, 0);
        accIm[1][0] = __builtin_amdgcn_mfma_f32_16x16x32_bf16(a21, b0, accIm[1][0], 0, 0, 0);
        accIm[1][1] = __builtin_amdgcn_mfma_f32_16x16x32_bf16(a21, b1, accIm[1][1], 0, 0, 0);
        __syncthreads();
    }
    #pragma unroll
    for (int i = 0; i < 2; i++)
        #pragma unroll
        for (int j = 0; j < 2; j++) {
            int k2 = nBase + wx * 32 + j * 16 + fm;
            #pragma unroll
            for (int r = 0; r < 4; r++) {
                int k1 = mBase + wy * 32 + i * 16 + (l >> 4) * 4 + r;
                G[((long)k1 * OSN + k2) * NCH + c] =
                    make_float2(accRe[i][j][r], accIm[i][j][r]);
            }
        }
}

// KB interpolation — GREEN (R13/R15). (imag, real) bf16 pack, c-major.
__global__ void interp_kernel(const float* __restrict__ trj,
                              const float2* __restrict__ grid,
                              u32* __restrict__ out) {
    const int t = threadIdx.x;
    const int c = t & 7;
    const int pl = t >> 3;
    __shared__ float wxs[32][6], wys[32][6];
    __shared__ int   x0s[32], y0s[32];

    if (t < 32) {
        int pt = blockIdx.x * 32 + t;
        float2 tv = *(const float2*)(trj + pt * 2);
        float cx = __fadd_rn(__fmul_rn(tv.x, 1.25f), 160.0f);
        float cy = __fadd_rn(__fmul_rn(tv.y, 1.25f), 160.0f);
        float x0 = ceilf(__fadd_rn(cx, -3.0f));
        float y0 = ceilf(__fadd_rn(cy, -3.0f));
        x0s[t] = (int)x0;
        y0s[t] = (int)y0;
        #pragma unroll
        for (int d = 0; d < 6; d++) {
            float u = __fdiv_rn(__fsub_rn(x0 + (float)d, cx), 3.0f);
            wxs[t][d] = i0f(BETA_F * sqrtf(fmaxf(1.0f - u * u, 0.0f)));
            float ww = __fdiv_rn(__fsub_rn(y0 + (float)d, cy), 3.0f);
            wys[t][d] = i0f(BETA_F * sqrtf(fmaxf(1.0f - ww * ww, 0.0f)));
        }
    }
    __syncthreads();

    int ix[6], iy[6];
    const int x0i = x0s[pl], y0i = y0s[pl];
    #pragma unroll
    for (int d = 0; d < 6; d++) {
        int vx = x0i + d;
        ix[d] = ((vx % OSN) + OSN) % OSN;
        int vy = y0i + d;
        iy[d] = ((vy % OSN) + OSN) % OSN;
    }

    float accRe = 0.f, accIm = 0.f;
    #pragma unroll
    for (int dx = 0; dx < 6; dx++) {
        long base = (long)ix[dx] * OSN;
        float wxv = wxs[pl][dx];
        #pragma unroll
        for (int dy = 0; dy < 6; dy++) {
            long gidx = (base + iy[dy]) * NCH + c;
            float2 g = grid[gidx];
            float ww = wxv * wys[pl][dy];
            accRe += g.x * ww;
            accIm += g.y * ww;
        }
    }
    accRe *= (1.0f / 36.0f);
    accIm *= (1.0f / 36.0f);

    __shared__ float2 lds[256];
    lds[t] = make_float2(accRe, accIm);
    __syncthreads();
    int c2 = t >> 5, p2 = t & 31;
    float2 v = lds[p2 * 8 + c2];
    out[(long)c2 * NPTS + blockIdx.x * 32 + p2] = f2bf(v.y) | (f2bf(v.x) << 16);
}

extern "C" void kernel_launch(void* const* d_in, const int* in_sizes, int n_in,
                              void* d_out, int out_size, void* d_ws, size_t ws_size,
                              hipStream_t stream) {
    const float* img_r = (const float*)d_in[0];
    const float* img_i = (const float*)d_in[1];
    const float* trj   = (const float*)d_in[2];

    // d_out (8,388,608 B) scratch layout (all dead before interp overwrites):
    //   Tb  @ 0         : 8*320*512*2  = 2,621,440 B  (bf16, [c][k2][kd])
    //   B1  @ 2,621,440 : 320*512*2    =   327,680 B
    //   B2  @ 2,949,120 : 320*512*2    =   327,680 B
    //   Abf @ 3,276,800 : 8*256*512*2  = 2,097,152 B  -> ends 5,373,952
    // d_ws: G (320*320*8 float2 = 6,553,600 B, proven safe).
    char* ob = (char*)d_out;
    short* Tb  = (short*)(ob);
    u32*  B1u  = (u32*)(ob + 2621440);
    u32*  B2u  = (u32*)(ob + 2949120);
    u32*  Au   = (u32*)(ob + 3276800);
    float2* G  = (float2*)d_ws;

    prep_const<<<(OSN * IMN) / 256, 256, 0, stream>>>(B1u, B2u);
    prep_a<<<(NCH * IMN * IMN) / 256, 256, 0, stream>>>(img_r, img_i, Au);
    gemm1<<<dim3(OSN / 64, IMN / 64, NCH), 256, 0, stream>>>(
        (const short*)Au, (const short*)B1u, (const short*)B2u, Tb);
    gemm2<<<dim3(OSN / 64, OSN / 64, NCH), 256, 0, stream>>>(
        (const short*)B1u, (const short*)B2u, Tb, G);
    interp_kernel<<<NPTS / 32, 256, 0, stream>>>(trj, G, (u32*)d_out);
}

// Round 17
// 126.414 us; speedup vs baseline: 4.8684x; 1.1587x over previous
//
#include <hip/hip_runtime.h>
#include <math.h>

// ---- problem constants ----
#define NCH   8
#define IMN   256
#define OSN   320
#define NPTS  (64*4096)            // 262144 trajectory points
#define KD    512                  // doubled K (re,im interleaved)
#define BETA_F   10.9551078f
#define BETA2_F  120.014389f
#define APOD_C   0.05890486225f    // pi*6/320

typedef unsigned short u16;
typedef unsigned int   u32;
typedef __attribute__((ext_vector_type(8))) short s16x8;   // 8 bf16 (4 VGPRs)
typedef __attribute__((ext_vector_type(4))) float f32x4;   // MFMA acc

__device__ __forceinline__ u32 f2bf(float f) {
    u32 u = __float_as_uint(f);
    return (u + 0x7FFFu + ((u >> 16) & 1u)) >> 16;
}

// Kaiser-Bessel i0 (A&S), rel err ~5e-7
__device__ __forceinline__ float i0f(float t) {
    if (t < 3.75f) {
        float y = t * t * (1.0f / 14.0625f);
        return 1.0f + y * (3.5156229f + y * (3.0899424f + y * (1.2067492f +
                     y * (0.2659732f + y * (0.0360768f + y * 0.0045813f)))));
    }
    float z = 3.75f / t;
    float p = 0.39894228f + z * (0.01328592f + z * (0.00225319f + z * (-0.00157565f +
              z * (0.00916281f + z * (-0.02057706f + z * (0.02635537f +
              z * (-0.01647633f + z * 0.00392377f)))))));
    return expf(t) * rsqrtf(t) * p;
}

__device__ __forceinline__ float apodf(int i) {
    float x = APOD_C * (float)(i - IMN / 2);
    float arg = sqrtf(BETA2_F - x * x);
    float e = expf(arg);
    float sh = 0.5f * (e - 1.0f / e);
    return arg / sh;
}

// B1[k][kd] = interleave(M2re, -M2im);  B2 = interleave(M2im, M2re)
// M2[k][j] = (-1)^(k+j) e^{-2pi i k(j+32)/320}  (green base)
__global__ void prep_const(u32* __restrict__ B1, u32* __restrict__ B2) {
    int idx = blockIdx.x * 256 + threadIdx.x;   // 320*256
    int k = idx >> 8, j = idx & 255;
    int p = (k * (j + 32)) % OSN;
    float th = (2.0f * (float)M_PI / (float)OSN) * (float)p;
    float s = ((k + j) & 1) ? -1.0f : 1.0f;
    float sn, cs;
    sincosf(th, &sn, &cs);
    float re = s * cs, im = -s * sn;
    B1[idx] = f2bf(re) | (f2bf(-im) << 16);
    B2[idx] = f2bf(im) | (f2bf(re) << 16);
}

// Abf[c][i1][kd]: apodized complex image, bf16, (re,im) interleaved along kd
__global__ void prep_a(const float* __restrict__ r, const float* __restrict__ im,
                       u32* __restrict__ A) {
    int idx = blockIdx.x * 256 + threadIdx.x;   // 8*256*256
    int i2 = idx & 255, i1 = (idx >> 8) & 255;
    float w = apodf(i1) * apodf(i2) * (1.0f / 256.0f);
    A[idx] = f2bf(r[idx] * w) | (f2bf(im[idx] * w) << 16);
}

// GEMM1 (MFMA): Tb[c][k2][kd], kd=2*i1(re),2*i1+1(im)
__launch_bounds__(256)
__global__ void gemm1(const short* __restrict__ Abf, const short* __restrict__ B1,
                      const short* __restrict__ B2, short* __restrict__ Tb) {
    const int c = blockIdx.z;
    const int mBase = blockIdx.y * 64;   // i1
    const int nBase = blockIdx.x * 64;   // k2
    __shared__ short As[64][40], B1s[64][40], B2s[64][40];
    const int t = threadIdx.x;
    const int l = t & 63, w = t >> 6;
    const int wy = w >> 1, wx = w & 1;
    const int row = t >> 2, seg = (t & 3) * 8;
    const int fm = l & 15, fq = (l >> 4) * 8;
    f32x4 zz = {0.f, 0.f, 0.f, 0.f};
    f32x4 accRe[2][2], accIm[2][2];
    #pragma unroll
    for (int i = 0; i < 2; i++)
        #pragma unroll
        for (int j = 0; j < 2; j++) { accRe[i][j] = zz; accIm[i][j] = zz; }

    for (int kc = 0; kc < 16; kc++) {
        const int kb = kc * 32 + seg;
        *(s16x8*)&As [row][seg] = *(const s16x8*)(Abf + ((long)(c * IMN + mBase + row)) * KD + kb);
        *(s16x8*)&B1s[row][seg] = *(const s16x8*)(B1 + (long)(nBase + row) * KD + kb);
        *(s16x8*)&B2s[row][seg] = *(const s16x8*)(B2 + (long)(nBase + row) * KD + kb);
        __syncthreads();
        s16x8 a0  = *(const s16x8*)&As [wy * 32 + fm][fq];
        s16x8 a1  = *(const s16x8*)&As [wy * 32 + 16 + fm][fq];
        s16x8 b10 = *(const s16x8*)&B1s[wx * 32 + fm][fq];
        s16x8 b11 = *(const s16x8*)&B1s[wx * 32 + 16 + fm][fq];
        s16x8 b20 = *(const s16x8*)&B2s[wx * 32 + fm][fq];
        s16x8 b21 = *(const s16x8*)&B2s[wx * 32 + 16 + fm][fq];
        accRe[0][0] = __builtin_amdgcn_mfma_f32_16x16x32_bf16(a0, b10, accRe[0][0], 0, 0, 0);
        accRe[0][1] = __builtin_amdgcn_mfma_f32_16x16x32_bf16(a0, b11, accRe[0][1], 0, 0, 0);
        accRe[1][0] = __builtin_amdgcn_mfma_f32_16x16x32_bf16(a1, b10, accRe[1][0], 0, 0, 0);
        accRe[1][1] = __builtin_amdgcn_mfma_f32_16x16x32_bf16(a1, b11, accRe[1][1], 0, 0, 0);
        accIm[0][0] = __builtin_amdgcn_mfma_f32_16x16x32_bf16(a0, b20, accIm[0][0], 0, 0, 0);
        accIm[0][1] = __builtin_amdgcn_mfma_f32_16x16x32_bf16(a0, b21, accIm[0][1], 0, 0, 0);
        accIm[1][0] = __builtin_amdgcn_mfma_f32_16x16x32_bf16(a1, b20, accIm[1][0], 0, 0, 0);
        accIm[1][1] = __builtin_amdgcn_mfma_f32_16x16x32_bf16(a1, b21, accIm[1][1], 0, 0, 0);
        __syncthreads();
    }
    #pragma unroll
    for (int i = 0; i < 2; i++)
        #pragma unroll
        for (int j = 0; j < 2; j++) {
            int i1b = mBase + wy * 32 + i * 16 + (l >> 4) * 4;
            int k2  = nBase + wx * 32 + j * 16 + fm;
            s16x8 v;
            #pragma unroll
            for (int r = 0; r < 4; r++) {
                v[2 * r]     = (short)f2bf(accRe[i][j][r]);
                v[2 * r + 1] = (short)f2bf(accIm[i][j][r]);
            }
            *(s16x8*)(Tb + ((long)(c * OSN + k2)) * KD + 2 * i1b) = v;
        }
}

// GEMM2 (MFMA): Gb[k1][k2][c] packed bf16 (re low, im high) — grid is
// 3.125 MB so it fits a 4 MiB per-XCD L2 (the R16 interp FETCH fix).
__launch_bounds__(256)
__global__ void gemm2(const short* __restrict__ B1, const short* __restrict__ B2,
                      const short* __restrict__ Tb, u32* __restrict__ Gb) {
    const int c = blockIdx.z;
    const int mBase = blockIdx.y * 64;   // k1
    const int nBase = blockIdx.x * 64;   // k2
    __shared__ short A1s[64][40], A2s[64][40], Bs[64][40];
    const int t = threadIdx.x;
    const int l = t & 63, w = t >> 6;
    const int wy = w >> 1, wx = w & 1;
    const int row = t >> 2, seg = (t & 3) * 8;
    const int fm = l & 15, fq = (l >> 4) * 8;
    f32x4 zz = {0.f, 0.f, 0.f, 0.f};
    f32x4 accRe[2][2], accIm[2][2];
    #pragma unroll
    for (int i = 0; i < 2; i++)
        #pragma unroll
        for (int j = 0; j < 2; j++) { accRe[i][j] = zz; accIm[i][j] = zz; }

    for (int kc = 0; kc < 16; kc++) {
        const int kb = kc * 32 + seg;
        *(s16x8*)&A1s[row][seg] = *(const s16x8*)(B1 + (long)(mBase + row) * KD + kb);
        *(s16x8*)&A2s[row][seg] = *(const s16x8*)(B2 + (long)(mBase + row) * KD + kb);
        *(s16x8*)&Bs [row][seg] = *(const s16x8*)(Tb + ((long)(c * OSN + nBase + row)) * KD + kb);
        __syncthreads();
        s16x8 a10 = *(const s16x8*)&A1s[wy * 32 + fm][fq];
        s16x8 a11 = *(const s16x8*)&A1s[wy * 32 + 16 + fm][fq];
        s16x8 a20 = *(const s16x8*)&A2s[wy * 32 + fm][fq];
        s16x8 a21 = *(const s16x8*)&A2s[wy * 32 + 16 + fm][fq];
        s16x8 b0  = *(const s16x8*)&Bs [wx * 32 + fm][fq];
        s16x8 b1  = *(const s16x8*)&Bs [wx * 32 + 16 + fm][fq];
        accRe[0][0] = __builtin_amdgcn_mfma_f32_16x16x32_bf16(a10, b0, accRe[0][0], 0, 0, 0);
        accRe[0][1] = __builtin_amdgcn_mfma_f32_16x16x32_bf16(a10, b1, accRe[0][1], 0, 0, 0);
        accRe[1][0] = __builtin_amdgcn_mfma_f32_16x16x32_bf16(a11, b0, accRe[1][0], 0, 0, 0);
        accRe[1][1] = __builtin_amdgcn_mfma_f32_16x16x32_bf16(a11, b1, accRe[1][1], 0, 0, 0);
        accIm[0][0] = __builtin_amdgcn_mfma_f32_16x16x32_bf16(a20, b0, accIm[0][0], 0, 0, 0);
        accIm[0][1] = __builtin_amdgcn_mfma_f32_16x16x32_bf16(a20, b1, accIm[0][1], 0, 0, 0);
        accIm[1][0] = __builtin_amdgcn_mfma_f32_16x16x32_bf16(a21, b0, accIm[1][0], 0, 0, 0);
        accIm[1][1] = __builtin_amdgcn_mfma_f32_16x16x32_bf16(a21, b1, accIm[1][1], 0, 0, 0);
        __syncthreads();
    }
    #pragma unroll
    for (int i = 0; i < 2; i++)
        #pragma unroll
        for (int j = 0; j < 2; j++) {
            int k2 = nBase + wx * 32 + j * 16 + fm;
            #pragma unroll
            for (int r = 0; r < 4; r++) {
                int k1 = mBase + wy * 32 + i * 16 + (l >> 4) * 4 + r;
                Gb[((long)k1 * OSN + k2) * NCH + c] =
                    f2bf(accRe[i][j][r]) | (f2bf(accIm[i][j][r]) << 16);
            }
        }
}

// KB interpolation — GREEN conventions. Grid now packed bf16 (4 B/gather).
__global__ void interp_kernel(const float* __restrict__ trj,
                              const u32* __restrict__ grid,
                              u32* __restrict__ out) {
    const int t = threadIdx.x;
    const int c = t & 7;
    const int pl = t >> 3;
    __shared__ float wxs[32][6], wys[32][6];
    __shared__ int   x0s[32], y0s[32];

    if (t < 32) {
        int pt = blockIdx.x * 32 + t;
        float2 tv = *(const float2*)(trj + pt * 2);
        float cx = __fadd_rn(__fmul_rn(tv.x, 1.25f), 160.0f);
        float cy = __fadd_rn(__fmul_rn(tv.y, 1.25f), 160.0f);
        float x0 = ceilf(__fadd_rn(cx, -3.0f));
        float y0 = ceilf(__fadd_rn(cy, -3.0f));
        x0s[t] = (int)x0;
        y0s[t] = (int)y0;
        #pragma unroll
        for (int d = 0; d < 6; d++) {
            float u = __fdiv_rn(__fsub_rn(x0 + (float)d, cx), 3.0f);
            wxs[t][d] = i0f(BETA_F * sqrtf(fmaxf(1.0f - u * u, 0.0f)));
            float ww = __fdiv_rn(__fsub_rn(y0 + (float)d, cy), 3.0f);
            wys[t][d] = i0f(BETA_F * sqrtf(fmaxf(1.0f - ww * ww, 0.0f)));
        }
    }
    __syncthreads();

    int ix[6], iy[6];
    const int x0i = x0s[pl], y0i = y0s[pl];
    #pragma unroll
    for (int d = 0; d < 6; d++) {
        int vx = x0i + d;
        ix[d] = ((vx % OSN) + OSN) % OSN;
        int vy = y0i + d;
        iy[d] = ((vy % OSN) + OSN) % OSN;
    }

    float accRe = 0.f, accIm = 0.f;
    #pragma unroll
    for (int dx = 0; dx < 6; dx++) {
        long base = (long)ix[dx] * OSN;
        float wxv = wxs[pl][dx];
        #pragma unroll
        for (int dy = 0; dy < 6; dy++) {
            u32 g = grid[(base + iy[dy]) * NCH + c];
            float gre = __uint_as_float(g << 16);
            float gim = __uint_as_float(g & 0xFFFF0000u);
            float ww = wxv * wys[pl][dy];
            accRe += gre * ww;
            accIm += gim * ww;
        }
    }
    accRe *= (1.0f / 36.0f);
    accIm *= (1.0f / 36.0f);

    __shared__ float2 lds[256];
    lds[t] = make_float2(accRe, accIm);
    __syncthreads();
    int c2 = t >> 5, p2 = t & 31;
    float2 v = lds[p2 * 8 + c2];
    // (imag, real) pack — verified green
    out[(long)c2 * NPTS + blockIdx.x * 32 + p2] = f2bf(v.y) | (f2bf(v.x) << 16);
}

extern "C" void kernel_launch(void* const* d_in, const int* in_sizes, int n_in,
                              void* d_out, int out_size, void* d_ws, size_t ws_size,
                              hipStream_t stream) {
    const float* img_r = (const float*)d_in[0];
    const float* img_i = (const float*)d_in[1];
    const float* trj   = (const float*)d_in[2];

    // d_out (8,388,608 B) scratch (dead before interp overwrites):
    //   Tb  @ 0         : 2,621,440 B   B1 @ 2,621,440 : 327,680 B
    //   B2  @ 2,949,120 :   327,680 B   Abf @ 3,276,800 : 2,097,152 B
    // d_ws: Gb packed bf16 grid, 320*320*8*4 = 3,276,800 B (< 4 MiB L2/XCD).
    char* ob = (char*)d_out;
    short* Tb  = (short*)(ob);
    u32*  B1u  = (u32*)(ob + 2621440);
    u32*  B2u  = (u32*)(ob + 2949120);
    u32*  Au   = (u32*)(ob + 3276800);
    u32*  Gb   = (u32*)d_ws;

    prep_const<<<(OSN * IMN) / 256, 256, 0, stream>>>(B1u, B2u);
    prep_a<<<(NCH * IMN * IMN) / 256, 256, 0, stream>>>(img_r, img_i, Au);
    gemm1<<<dim3(OSN / 64, IMN / 64, NCH), 256, 0, stream>>>(
        (const short*)Au, (const short*)B1u, (const short*)B2u, Tb);
    gemm2<<<dim3(OSN / 64, OSN / 64, NCH), 256, 0, stream>>>(
        (const short*)B1u, (const short*)B2u, Tb, Gb);
    interp_kernel<<<NPTS / 32, 256, 0, stream>>>(trj, Gb, (u32*)d_out);
}

// Round 18
// 116.501 us; speedup vs baseline: 5.2826x; 1.0851x over previous
//
#include <hip/hip_runtime.h>
#include <math.h>

// ---- problem constants ----
#define NCH   8
#define IMN   256
#define OSN   320
#define NPTS  (64*4096)            // 262144 trajectory points
#define KD    512                  // doubled K (re,im interleaved)
#define BETA_F   10.9551078f
#define BETA2_F  120.014389f
#define APOD_C   0.05890486225f    // pi*6/320

typedef unsigned short u16;
typedef unsigned int   u32;
typedef __attribute__((ext_vector_type(8))) short s16x8;   // 8 bf16 (4 VGPRs)
typedef __attribute__((ext_vector_type(4))) float f32x4;   // MFMA acc

__device__ __forceinline__ u32 f2bf(float f) {
    u32 u = __float_as_uint(f);
    return (u + 0x7FFFu + ((u >> 16) & 1u)) >> 16;
}

// Kaiser-Bessel i0 (A&S), rel err ~5e-7
__device__ __forceinline__ float i0f(float t) {
    if (t < 3.75f) {
        float y = t * t * (1.0f / 14.0625f);
        return 1.0f + y * (3.5156229f + y * (3.0899424f + y * (1.2067492f +
                     y * (0.2659732f + y * (0.0360768f + y * 0.0045813f)))));
    }
    float z = 3.75f / t;
    float p = 0.39894228f + z * (0.01328592f + z * (0.00225319f + z * (-0.00157565f +
              z * (0.00916281f + z * (-0.02057706f + z * (0.02635537f +
              z * (-0.01647633f + z * 0.00392377f)))))));
    return expf(t) * rsqrtf(t) * p;
}

__device__ __forceinline__ float apodf(int i) {
    float x = APOD_C * (float)(i - IMN / 2);
    float arg = sqrtf(BETA2_F - x * x);
    float e = expf(arg);
    float sh = 0.5f * (e - 1.0f / e);
    return arg / sh;
}

// B1[k][kd] = interleave(M2re, -M2im);  B2 = interleave(M2im, M2re)
__global__ void prep_const(u32* __restrict__ B1, u32* __restrict__ B2) {
    int idx = blockIdx.x * 256 + threadIdx.x;   // 320*256
    int k = idx >> 8, j = idx & 255;
    int p = (k * (j + 32)) % OSN;
    float th = (2.0f * (float)M_PI / (float)OSN) * (float)p;
    float s = ((k + j) & 1) ? -1.0f : 1.0f;
    float sn, cs;
    sincosf(th, &sn, &cs);
    float re = s * cs, im = -s * sn;
    B1[idx] = f2bf(re) | (f2bf(-im) << 16);
    B2[idx] = f2bf(im) | (f2bf(re) << 16);
}

// Abf[c][i1][kd]: apodized complex image, bf16, (re,im) interleaved along kd
__global__ void prep_a(const float* __restrict__ r, const float* __restrict__ im,
                       u32* __restrict__ A) {
    int idx = blockIdx.x * 256 + threadIdx.x;   // 8*256*256
    int i2 = idx & 255, i1 = (idx >> 8) & 255;
    float w = apodf(i1) * apodf(i2) * (1.0f / 256.0f);
    A[idx] = f2bf(r[idx] * w) | (f2bf(im[idx] * w) << 16);
}

// GEMM1 (MFMA): Tb[c][k2][kd], kd=2*i1(re),2*i1+1(im).
// 64(M=i1) x 32(N=k2) tile, 128 threads (2 waves), grid (10,4,8)=320 blocks.
__launch_bounds__(128)
__global__ void gemm1(const short* __restrict__ Abf, const short* __restrict__ B1,
                      const short* __restrict__ B2, short* __restrict__ Tb) {
    const int c = blockIdx.z;
    const int mBase = blockIdx.y * 64;   // i1
    const int nBase = blockIdx.x * 32;   // k2
    __shared__ short As[64][40], B1s[32][40], B2s[32][40];
    const int t = threadIdx.x;
    const int l = t & 63, w = t >> 6;
    const int arow = t >> 1, aseg = (t & 1) * 16;
    const int brow = t >> 2, bseg = (t & 3) * 8;
    const int fm = l & 15, fq = (l >> 4) * 8;
    f32x4 zz = {0.f, 0.f, 0.f, 0.f};
    f32x4 accRe[2][2], accIm[2][2];
    #pragma unroll
    for (int i = 0; i < 2; i++)
        #pragma unroll
        for (int j = 0; j < 2; j++) { accRe[i][j] = zz; accIm[i][j] = zz; }

    for (int kc = 0; kc < 16; kc++) {
        const int kb = kc * 32;
        {
            const short* ap = Abf + ((long)(c * IMN + mBase + arow)) * KD + kb + aseg;
            *(s16x8*)&As[arow][aseg]     = *(const s16x8*)(ap);
            *(s16x8*)&As[arow][aseg + 8] = *(const s16x8*)(ap + 8);
        }
        *(s16x8*)&B1s[brow][bseg] = *(const s16x8*)(B1 + (long)(nBase + brow) * KD + kb + bseg);
        *(s16x8*)&B2s[brow][bseg] = *(const s16x8*)(B2 + (long)(nBase + brow) * KD + kb + bseg);
        __syncthreads();
        s16x8 a0  = *(const s16x8*)&As [w * 32 + fm][fq];
        s16x8 a1  = *(const s16x8*)&As [w * 32 + 16 + fm][fq];
        s16x8 b10 = *(const s16x8*)&B1s[fm][fq];
        s16x8 b11 = *(const s16x8*)&B1s[16 + fm][fq];
        s16x8 b20 = *(const s16x8*)&B2s[fm][fq];
        s16x8 b21 = *(const s16x8*)&B2s[16 + fm][fq];
        accRe[0][0] = __builtin_amdgcn_mfma_f32_16x16x32_bf16(a0, b10, accRe[0][0], 0, 0, 0);
        accRe[0][1] = __builtin_amdgcn_mfma_f32_16x16x32_bf16(a0, b11, accRe[0][1], 0, 0, 0);
        accRe[1][0] = __builtin_amdgcn_mfma_f32_16x16x32_bf16(a1, b10, accRe[1][0], 0, 0, 0);
        accRe[1][1] = __builtin_amdgcn_mfma_f32_16x16x32_bf16(a1, b11, accRe[1][1], 0, 0, 0);
        accIm[0][0] = __builtin_amdgcn_mfma_f32_16x16x32_bf16(a0, b20, accIm[0][0], 0, 0, 0);
        accIm[0][1] = __builtin_amdgcn_mfma_f32_16x16x32_bf16(a0, b21, accIm[0][1], 0, 0, 0);
        accIm[1][0] = __builtin_amdgcn_mfma_f32_16x16x32_bf16(a1, b20, accIm[1][0], 0, 0, 0);
        accIm[1][1] = __builtin_amdgcn_mfma_f32_16x16x32_bf16(a1, b21, accIm[1][1], 0, 0, 0);
        __syncthreads();
    }
    // C/D layout: col = lane&15, row = (lane>>4)*4 + reg
    #pragma unroll
    for (int i = 0; i < 2; i++)
        #pragma unroll
        for (int j = 0; j < 2; j++) {
            int i1b = mBase + w * 32 + i * 16 + (l >> 4) * 4;
            int k2  = nBase + j * 16 + fm;
            s16x8 v;
            #pragma unroll
            for (int r = 0; r < 4; r++) {
                v[2 * r]     = (short)f2bf(accRe[i][j][r]);
                v[2 * r + 1] = (short)f2bf(accIm[i][j][r]);
            }
            *(s16x8*)(Tb + ((long)(c * OSN + k2)) * KD + 2 * i1b) = v;
        }
}

// GEMM2 (MFMA): Gb[k1][k2][c] packed bf16. 64(M=k1) x 32(N=k2) tile,
// 128 threads, grid (10,5,8)=400 blocks.
__launch_bounds__(128)
__global__ void gemm2(const short* __restrict__ B1, const short* __restrict__ B2,
                      const short* __restrict__ Tb, u32* __restrict__ Gb) {
    const int c = blockIdx.z;
    const int mBase = blockIdx.y * 64;   // k1
    const int nBase = blockIdx.x * 32;   // k2
    __shared__ short A1s[64][40], A2s[64][40], Bs[32][40];
    const int t = threadIdx.x;
    const int l = t & 63, w = t >> 6;
    const int arow = t >> 1, aseg = (t & 1) * 16;
    const int brow = t >> 2, bseg = (t & 3) * 8;
    const int fm = l & 15, fq = (l >> 4) * 8;
    f32x4 zz = {0.f, 0.f, 0.f, 0.f};
    f32x4 accRe[2][2], accIm[2][2];
    #pragma unroll
    for (int i = 0; i < 2; i++)
        #pragma unroll
        for (int j = 0; j < 2; j++) { accRe[i][j] = zz; accIm[i][j] = zz; }

    for (int kc = 0; kc < 16; kc++) {
        const int kb = kc * 32;
        {
            const short* a1p = B1 + (long)(mBase + arow) * KD + kb + aseg;
            const short* a2p = B2 + (long)(mBase + arow) * KD + kb + aseg;
            *(s16x8*)&A1s[arow][aseg]     = *(const s16x8*)(a1p);
            *(s16x8*)&A1s[arow][aseg + 8] = *(const s16x8*)(a1p + 8);
            *(s16x8*)&A2s[arow][aseg]     = *(const s16x8*)(a2p);
            *(s16x8*)&A2s[arow][aseg + 8] = *(const s16x8*)(a2p + 8);
        }
        *(s16x8*)&Bs[brow][bseg] = *(const s16x8*)(Tb + ((long)(c * OSN + nBase + brow)) * KD + kb + bseg);
        __syncthreads();
        s16x8 a10 = *(const s16x8*)&A1s[w * 32 + fm][fq];
        s16x8 a11 = *(const s16x8*)&A1s[w * 32 + 16 + fm][fq];
        s16x8 a20 = *(const s16x8*)&A2s[w * 32 + fm][fq];
        s16x8 a21 = *(const s16x8*)&A2s[w * 32 + 16 + fm][fq];
        s16x8 b0  = *(const s16x8*)&Bs [fm][fq];
        s16x8 b1  = *(const s16x8*)&Bs [16 + fm][fq];
        accRe[0][0] = __builtin_amdgcn_mfma_f32_16x16x32_bf16(a10, b0, accRe[0][0], 0, 0, 0);
        accRe[0][1] = __builtin_amdgcn_mfma_f32_16x16x32_bf16(a10, b1, accRe[0][1], 0, 0, 0);
        accRe[1][0] = __builtin_amdgcn_mfma_f32_16x16x32_bf16(a11, b0, accRe[1][0], 0, 0, 0);
        accRe[1][1] = __builtin_amdgcn_mfma_f32_16x16x32_bf16(a11, b1, accRe[1][1], 0, 0, 0);
        accIm[0][0] = __builtin_amdgcn_mfma_f32_16x16x32_bf16(a20, b0, accIm[0][0], 0, 0, 0);
        accIm[0][1] = __builtin_amdgcn_mfma_f32_16x16x32_bf16(a20, b1, accIm[0][1], 0, 0, 0);
        accIm[1][0] = __builtin_amdgcn_mfma_f32_16x16x32_bf16(a21, b0, accIm[1][0], 0, 0, 0);
        accIm[1][1] = __builtin_amdgcn_mfma_f32_16x16x32_bf16(a21, b1, accIm[1][1], 0, 0, 0);
        __syncthreads();
    }
    #pragma unroll
    for (int i = 0; i < 2; i++)
        #pragma unroll
        for (int j = 0; j < 2; j++) {
            int k2 = nBase + j * 16 + fm;
            #pragma unroll
            for (int r = 0; r < 4; r++) {
                int k1 = mBase + w * 32 + i * 16 + (l >> 4) * 4 + r;
                Gb[((long)k1 * OSN + k2) * NCH + c] =
                    f2bf(accRe[i][j][r]) | (f2bf(accIm[i][j][r]) << 16);
            }
        }
}

// KB interpolation — GREEN conventions, packed-bf16 grid.
// R18: 64 points/block, 4 lanes/point x 2 channels per uint2 load:
// halves load+address instruction count; per-channel accumulation order
// unchanged -> bit-identical values.
__global__ void interp_kernel(const float* __restrict__ trj,
                              const u32* __restrict__ grid,
                              u32* __restrict__ out) {
    const int t = threadIdx.x;
    const int pl = t >> 2;                   // point 0..63
    const int cp = (t & 3) * 2;              // channel pair base
    __shared__ float wxs[64][6], wys[64][6];
    __shared__ int   x0s[64], y0s[64];

    if (t < 64) {
        int pt = blockIdx.x * 64 + t;
        float2 tv = *(const float2*)(trj + pt * 2);
        float cx = __fadd_rn(__fmul_rn(tv.x, 1.25f), 160.0f);
        float cy = __fadd_rn(__fmul_rn(tv.y, 1.25f), 160.0f);
        float x0 = ceilf(__fadd_rn(cx, -3.0f));
        float y0 = ceilf(__fadd_rn(cy, -3.0f));
        x0s[t] = (int)x0;
        y0s[t] = (int)y0;
        #pragma unroll
        for (int d = 0; d < 6; d++) {
            float u = __fdiv_rn(__fsub_rn(x0 + (float)d, cx), 3.0f);
            wxs[t][d] = i0f(BETA_F * sqrtf(fmaxf(1.0f - u * u, 0.0f)));
            float ww = __fdiv_rn(__fsub_rn(y0 + (float)d, cy), 3.0f);
            wys[t][d] = i0f(BETA_F * sqrtf(fmaxf(1.0f - ww * ww, 0.0f)));
        }
    }
    __syncthreads();

    int ix[6], iy[6];
    const int x0i = x0s[pl], y0i = y0s[pl];
    #pragma unroll
    for (int d = 0; d < 6; d++) {
        int vx = x0i + d;
        ix[d] = ((vx % OSN) + OSN) % OSN;
        int vy = y0i + d;
        iy[d] = ((vy % OSN) + OSN) % OSN;
    }

    float re0 = 0.f, im0 = 0.f, re1 = 0.f, im1 = 0.f;
    #pragma unroll
    for (int dx = 0; dx < 6; dx++) {
        long base = (long)ix[dx] * OSN;
        float wxv = wxs[pl][dx];
        #pragma unroll
        for (int dy = 0; dy < 6; dy++) {
            uint2 g = *(const uint2*)(grid + (base + iy[dy]) * NCH + cp);
            float ww = wxv * wys[pl][dy];
            re0 += __uint_as_float(g.x << 16) * ww;
            im0 += __uint_as_float(g.x & 0xFFFF0000u) * ww;
            re1 += __uint_as_float(g.y << 16) * ww;
            im1 += __uint_as_float(g.y & 0xFFFF0000u) * ww;
        }
    }
    re0 *= (1.0f / 36.0f); im0 *= (1.0f / 36.0f);
    re1 *= (1.0f / 36.0f); im1 *= (1.0f / 36.0f);

    __shared__ float2 lds[64 * 8];           // [point][channel]
    lds[pl * 8 + cp]     = make_float2(re0, im0);
    lds[pl * 8 + cp + 1] = make_float2(re1, im1);
    __syncthreads();
    // writes: 8 ch x 64 pts = 512 u32; thread writes pts p2 and p2+32 of ch c2
    int c2 = t >> 5, p2 = t & 31;
    float2 va = lds[p2 * 8 + c2];
    float2 vb = lds[(p2 + 32) * 8 + c2];
    long ob = (long)c2 * NPTS + blockIdx.x * 64;
    out[ob + p2]      = f2bf(va.y) | (f2bf(va.x) << 16);   // (imag, real) pack
    out[ob + p2 + 32] = f2bf(vb.y) | (f2bf(vb.x) << 16);
}

extern "C" void kernel_launch(void* const* d_in, const int* in_sizes, int n_in,
                              void* d_out, int out_size, void* d_ws, size_t ws_size,
                              hipStream_t stream) {
    const float* img_r = (const float*)d_in[0];
    const float* img_i = (const float*)d_in[1];
    const float* trj   = (const float*)d_in[2];

    // d_out (8,388,608 B) scratch (dead before interp overwrites):
    //   Tb @ 0 : 2,621,440 B   B1 @ 2,621,440 : 327,680 B
    //   B2 @ 2,949,120 : 327,680 B   Abf @ 3,276,800 : 2,097,152 B
    // d_ws: Gb packed bf16 grid, 3,276,800 B (< 4 MiB L2/XCD).
    char* ob = (char*)d_out;
    short* Tb  = (short*)(ob);
    u32*  B1u  = (u32*)(ob + 2621440);
    u32*  B2u  = (u32*)(ob + 2949120);
    u32*  Au   = (u32*)(ob + 3276800);
    u32*  Gb   = (u32*)d_ws;

    prep_const<<<(OSN * IMN) / 256, 256, 0, stream>>>(B1u, B2u);
    prep_a<<<(NCH * IMN * IMN) / 256, 256, 0, stream>>>(img_r, img_i, Au);
    gemm1<<<dim3(OSN / 32, IMN / 64, NCH), 128, 0, stream>>>(
        (const short*)Au, (const short*)B1u, (const short*)B2u, Tb);
    gemm2<<<dim3(OSN / 32, OSN / 64, NCH), 128, 0, stream>>>(
        (const short*)B1u, (const short*)B2u, Tb, Gb);
    interp_kernel<<<NPTS / 64, 256, 0, stream>>>(trj, Gb, (u32*)d_out);
}